// Round 1
// baseline (1601.538 us; speedup 1.0000x reference)
//
#include <hip/hip_runtime.h>

typedef unsigned short u16;
typedef __attribute__((ext_vector_type(8))) short short8;
typedef __attribute__((ext_vector_type(4))) float f32x4;

#define NB 1024
#define TT 64
#define CC 768
#define HH 12
#define HD 64
#define MLP 3072

__device__ __forceinline__ float b2f(u16 u) {
    return __uint_as_float(((unsigned)u) << 16);
}
__device__ __forceinline__ u16 f2b(float f) {
    unsigned u = __float_as_uint(f);
    unsigned r = (u + 0x7fff + ((u >> 16) & 1)) >> 16;
    return (u16)r;
}

__device__ __forceinline__ void block_reduce2(float& a, float& b, float* rbuf, int tid) {
#pragma unroll
    for (int off = 32; off > 0; off >>= 1) {
        a += __shfl_down(a, off, 64);
        b += __shfl_down(b, off, 64);
    }
    int wid = tid >> 6, lane = tid & 63;
    if (lane == 0) { rbuf[wid] = a; rbuf[wid + 4] = b; }
    __syncthreads();
    a = rbuf[0] + rbuf[1] + rbuf[2] + rbuf[3];
    b = rbuf[4] + rbuf[5] + rbuf[6] + rbuf[7];
    __syncthreads();
}

// ---------------- init / misc kernels ----------------

__global__ __launch_bounds__(256) void init_x_kernel(const float* __restrict__ cls, float* __restrict__ x) {
    int idx = blockIdx.x * 256 + threadIdx.x;  // < 786432
    x[idx] = cls[idx % CC];
}

__global__ __launch_bounds__(256) void store_out_kernel(const float* __restrict__ x, float* __restrict__ out) {
    int idx = blockIdx.x * 256 + threadIdx.x;
    out[idx] = x[idx];
}

// wkT[l][i][c] = wk[l][c][i], fp32 -> bf16
__global__ __launch_bounds__(256) void transpose_k_kernel(const float* __restrict__ wk, u16* __restrict__ wkT) {
    __shared__ float tile[32][33];
    int l = blockIdx.z;
    const float* src = wk + (long)l * (CC * CC);
    u16* dst = wkT + (long)l * (CC * CC);
    int i0 = blockIdx.x * 32, c0 = blockIdx.y * 32;
    int tx = threadIdx.x & 31, ty = threadIdx.x >> 5;  // ty 0..7
#pragma unroll
    for (int u = 0; u < 4; ++u)
        tile[ty + 8 * u][tx] = src[(long)(c0 + ty + 8 * u) * CC + i0 + tx];
    __syncthreads();
#pragma unroll
    for (int u = 0; u < 4; ++u)
        dst[(long)(i0 + ty + 8 * u) * CC + c0 + tx] = f2b(tile[tx][ty + 8 * u]);
}

// LN over C=768 of fp32 x -> bf16 out, with fp32 gamma/beta
__global__ __launch_bounds__(256) void ln_kernel(const float* __restrict__ x, const float* __restrict__ g,
                                                 const float* __restrict__ b, u16* __restrict__ out) {
    __shared__ float rbuf[8];
    int n = blockIdx.x, tid = threadIdx.x;
    const float* xr = x + (long)n * CC;
    float v0 = xr[tid], v1 = xr[tid + 256], v2 = xr[tid + 512];
    float s = v0 + v1 + v2, ss = v0 * v0 + v1 * v1 + v2 * v2;
    block_reduce2(s, ss, rbuf, tid);
    float mu = s * (1.0f / 768.0f);
    float rs = rsqrtf(ss * (1.0f / 768.0f) - mu * mu + 1e-5f);
    u16* orow = out + (long)n * CC;
    orow[tid]       = f2b((v0 - mu) * rs * g[tid]       + b[tid]);
    orow[tid + 256] = f2b((v1 - mu) * rs * g[tid + 256] + b[tid + 256]);
    orow[tid + 512] = f2b((v2 - mu) * rs * g[tid + 512] + b[tid + 512]);
}

// qb[n*12+h] = sum_d q[n, h*64+d] * bk[h*64+d]
__global__ __launch_bounds__(256) void qb_kernel(const u16* __restrict__ q, const float* __restrict__ bk,
                                                 float* __restrict__ qb) {
    int lane = threadIdx.x & 63;
    int idx = blockIdx.x * 4 + (threadIdx.x >> 6);  // n*12+h
    int n = idx / 12, h = idx - n * 12;
    float v = b2f(q[(long)n * CC + h * 64 + lane]) * bk[h * 64 + lane];
#pragma unroll
    for (int off = 32; off > 0; off >>= 1) v += __shfl_down(v, off, 64);
    if (lane == 0) qb[idx] = v;
}

// ---------------- generic MFMA GEMM (64x64 tile, K-step 32) ----------------
template <int ACC_F32, int GELU, int HAS_BIAS, int B_F32>
__global__ __launch_bounds__(256) void gemm_kernel(const u16* __restrict__ A, int lda, long a_zoff,
                                                   const void* __restrict__ Bv, int ldb, long b_zoff,
                                                   void* __restrict__ Cout, int ldc, long c_zoff,
                                                   const float* __restrict__ bias, long bias_zoff,
                                                   int K) {
    __shared__ u16 As[64 * 40];
    __shared__ u16 Bs[64 * 40];
    const int tid = threadIdx.x;
    const int z = blockIdx.z;
    A += (long)z * a_zoff;
    const float* Bf = B_F32 ? ((const float*)Bv + (long)z * b_zoff) : nullptr;
    const u16* Bh = B_F32 ? nullptr : ((const u16*)Bv + (long)z * b_zoff);
    const float* bias_p = HAS_BIAS ? bias + (long)z * bias_zoff : nullptr;
    const long c_base = (long)z * c_zoff;
    const int m0 = blockIdx.y * 64;
    const int n0 = blockIdx.x * 64;

    const int am = tid >> 2;
    const int ak = (tid & 3) * 8;
    const int bn = tid & 63;
    const int bk = (tid >> 6) * 8;

    const int lane = tid & 63;
    const int wid = tid >> 6;
    const int wm = (wid >> 1) * 32, wn = (wid & 1) * 32;
    const int l15 = lane & 15, q4 = lane >> 4;

    f32x4 acc[2][2] = {};

    for (int k0 = 0; k0 < K; k0 += 32) {
        int4 av = *(const int4*)(A + (long)(m0 + am) * lda + k0 + ak);
        unsigned bv0, bv1, bv2, bv3;
        if (B_F32) {
            const float* bp = Bf + (long)(k0 + bk) * ldb + n0 + bn;
            u16 e0 = f2b(bp[0]);
            u16 e1 = f2b(bp[(long)ldb]);
            u16 e2 = f2b(bp[(long)ldb * 2]);
            u16 e3 = f2b(bp[(long)ldb * 3]);
            u16 e4 = f2b(bp[(long)ldb * 4]);
            u16 e5 = f2b(bp[(long)ldb * 5]);
            u16 e6 = f2b(bp[(long)ldb * 6]);
            u16 e7 = f2b(bp[(long)ldb * 7]);
            bv0 = (unsigned)e0 | ((unsigned)e1 << 16); bv1 = (unsigned)e2 | ((unsigned)e3 << 16);
            bv2 = (unsigned)e4 | ((unsigned)e5 << 16); bv3 = (unsigned)e6 | ((unsigned)e7 << 16);
        } else {
            const u16* bp = Bh + (long)(k0 + bk) * ldb + n0 + bn;
            unsigned e0 = bp[0];
            unsigned e1 = bp[(long)ldb];
            unsigned e2 = bp[(long)ldb * 2];
            unsigned e3 = bp[(long)ldb * 3];
            unsigned e4 = bp[(long)ldb * 4];
            unsigned e5 = bp[(long)ldb * 5];
            unsigned e6 = bp[(long)ldb * 6];
            unsigned e7 = bp[(long)ldb * 7];
            bv0 = e0 | (e1 << 16); bv1 = e2 | (e3 << 16);
            bv2 = e4 | (e5 << 16); bv3 = e6 | (e7 << 16);
        }
        __syncthreads();
        *(int4*)(As + am * 40 + ak) = av;
        int4 bvv; bvv.x = (int)bv0; bvv.y = (int)bv1; bvv.z = (int)bv2; bvv.w = (int)bv3;
        *(int4*)(Bs + bn * 40 + bk) = bvv;  // Bs[n][k]
        __syncthreads();

        short8 a_f[2], b_f[2];
        a_f[0] = *(const short8*)(As + (wm + l15) * 40 + q4 * 8);
        a_f[1] = *(const short8*)(As + (wm + 16 + l15) * 40 + q4 * 8);
        b_f[0] = *(const short8*)(Bs + (wn + l15) * 40 + q4 * 8);
        b_f[1] = *(const short8*)(Bs + (wn + 16 + l15) * 40 + q4 * 8);
#pragma unroll
        for (int i = 0; i < 2; ++i)
#pragma unroll
            for (int j = 0; j < 2; ++j)
                acc[i][j] = __builtin_amdgcn_mfma_f32_16x16x32_bf16(a_f[i], b_f[j], acc[i][j], 0, 0, 0);
    }

#pragma unroll
    for (int i = 0; i < 2; ++i) {
#pragma unroll
        for (int j = 0; j < 2; ++j) {
            int row = m0 + wm + i * 16 + q4 * 4;
            int col = n0 + wn + j * 16 + l15;
            float bias_v = 0.f;
            if (HAS_BIAS) bias_v = bias_p[col];
#pragma unroll
            for (int r = 0; r < 4; ++r) {
                float v = acc[i][j][r] + bias_v;
                if (GELU) v = v / (1.0f + __expf(-1.702f * v));
                if (ACC_F32) {
                    float* Cf = (float*)Cout + c_base;
                    Cf[(long)(row + r) * ldc + col] += v;
                } else {
                    u16* Cb = (u16*)Cout + c_base;
                    Cb[(long)(row + r) * ldc + col] = f2b(v);
                }
            }
        }
    }
}

// ---------------- fused attention kernel v2 (one block per sample) ----------------
// Per chunk of 16 t-rows:
//   phase A: each wave LNs 4 rows (conv+pe+residual) with wave-only reductions -> yn_s
//   phase B: wave 0 computes aff(16x12) = yn @ qp^T via MFMA
//   phase C: 12 threads do online-softmax update (m,l,alpha; p stored in aff_s)
//   phase D: all waves: sacc = sacc*alpha + p^T @ yn via MFMA (K zero-padded to 32)
__global__ __launch_bounds__(256, 2) void attn_kernel(const float* __restrict__ inf, const int* __restrict__ mask,
                                                      const float* __restrict__ cw, const float* __restrict__ cb,
                                                      const float* __restrict__ pe, const float* __restrict__ g3,
                                                      const float* __restrict__ b3, const u16* __restrict__ qproj,
                                                      const float* __restrict__ qb, u16* __restrict__ s_out) {
    __shared__ u16 yn_s[16 * 776];    // 24832 B
    __shared__ u16 qp_s[16 * 776];    // 24832 B (rows 12..15 uninit, only read into discarded lanes)
    __shared__ float aff_s[16 * 13];  // 832 B
    __shared__ float qb_s[12];
    __shared__ float mh_s[16], lh_s[16], al_s[16];
    __shared__ int msk_s[64];

    const int tid = threadIdx.x;
    const int lane = tid & 63;
    const int wid = tid >> 6;
    const int l15 = lane & 15, q4 = lane >> 4;
    const int n = blockIdx.x;
    const long ibase = (long)n * (TT * CC);
    const int c0 = lane * 4;  // channels c0+256j+q, j=0..2, q=0..3

    // stage qproj[n] (12 rows of 768 bf16) into qp_s (776-stride)
    for (int idx = tid * 8; idx < HH * CC; idx += 256 * 8) {
        uint4 v = *(const uint4*)(qproj + (long)n * (HH * CC) + idx);
        int h = idx / CC, c = idx - h * CC;
        *(uint4*)(qp_s + h * 776 + c) = v;
    }
    if (tid < 12) qb_s[tid] = qb[n * 12 + tid];
    if (tid < 16) { mh_s[tid] = -1e30f; lh_s[tid] = 0.f; al_s[tid] = 1.f; }
    if (tid < 64) msk_s[tid] = mask[n * TT + tid];

    // per-thread conv/LN constants for its 12 channels
    float cw0a[12], cw1a[12], cw2a[12], cba[12], ga[12], ba[12];
#pragma unroll
    for (int j = 0; j < 3; ++j) {
        int c = c0 + 256 * j;
        *(float4*)(cba + 4 * j) = *(const float4*)(cb + c);
        *(float4*)(ga + 4 * j) = *(const float4*)(g3 + c);
        *(float4*)(ba + 4 * j) = *(const float4*)(b3 + c);
#pragma unroll
        for (int q = 0; q < 4; ++q) {
            cw0a[j * 4 + q] = cw[(c + q) * 3 + 0];
            cw1a[j * 4 + q] = cw[(c + q) * 3 + 1];
            cw2a[j * 4 + q] = cw[(c + q) * 3 + 2];
        }
    }

    f32x4 sacc[12] = {};  // s accumulator: h = q4*4+r (rows), c = (wid*12+jt)*16 + l15

    for (int tc = 0; tc < 4; ++tc) {
        const int t0 = tc * 16 + wid * 4;
        // ---- phase A: 4 rows per wave, wave-level reductions only ----
        float pva[12], cva[12], nva[12];
#pragma unroll
        for (int j = 0; j < 3; ++j) {
            int c = c0 + 256 * j;
            if (t0 > 0)
                *(float4*)(pva + 4 * j) = *(const float4*)(inf + ibase + (long)(t0 - 1) * CC + c);
            else
                *(float4*)(pva + 4 * j) = make_float4(0.f, 0.f, 0.f, 0.f);
            *(float4*)(cva + 4 * j) = *(const float4*)(inf + ibase + (long)t0 * CC + c);
        }
#pragma unroll
        for (int r = 0; r < 4; ++r) {
            const int t = t0 + r;
#pragma unroll
            for (int j = 0; j < 3; ++j) {
                int c = c0 + 256 * j;
                if (t < 63)
                    *(float4*)(nva + 4 * j) = *(const float4*)(inf + ibase + (long)(t + 1) * CC + c);
                else
                    *(float4*)(nva + 4 * j) = make_float4(0.f, 0.f, 0.f, 0.f);
            }
            float pev[12];
#pragma unroll
            for (int j = 0; j < 3; ++j)
                *(float4*)(pev + 4 * j) = *(const float4*)(pe + (long)t * CC + c0 + 256 * j);
            float y[12];
            float sm = 0.f, sq = 0.f;
#pragma unroll
            for (int q = 0; q < 12; ++q) {
                float yy = cva[q] + cw0a[q] * pva[q] + cw1a[q] * cva[q] + cw2a[q] * nva[q] + cba[q] + pev[q];
                y[q] = yy;
                sm += yy;
                sq += yy * yy;
            }
#pragma unroll
            for (int off = 32; off > 0; off >>= 1) {
                sm += __shfl_xor(sm, off, 64);
                sq += __shfl_xor(sq, off, 64);
            }
            float mu = sm * (1.0f / 768.0f);
            float rs = rsqrtf(sq * (1.0f / 768.0f) - mu * mu + 1e-5f);
#pragma unroll
            for (int j = 0; j < 3; ++j) {
                int c = c0 + 256 * j;
                unsigned w0 = (unsigned)f2b((y[j * 4 + 0] - mu) * rs * ga[j * 4 + 0] + ba[j * 4 + 0]) |
                              ((unsigned)f2b((y[j * 4 + 1] - mu) * rs * ga[j * 4 + 1] + ba[j * 4 + 1]) << 16);
                unsigned w1 = (unsigned)f2b((y[j * 4 + 2] - mu) * rs * ga[j * 4 + 2] + ba[j * 4 + 2]) |
                              ((unsigned)f2b((y[j * 4 + 3] - mu) * rs * ga[j * 4 + 3] + ba[j * 4 + 3]) << 16);
                *(uint2*)(yn_s + (wid * 4 + r) * 776 + c) = make_uint2(w0, w1);
            }
#pragma unroll
            for (int q = 0; q < 12; ++q) { pva[q] = cva[q]; cva[q] = nva[q]; }
        }
        __syncthreads();
        // ---- phase B: aff via MFMA (wave 0) ----
        if (wid == 0) {
            f32x4 aacc = {0.f, 0.f, 0.f, 0.f};
#pragma unroll 4
            for (int k0 = 0; k0 < CC; k0 += 32) {
                short8 a = *(const short8*)(yn_s + l15 * 776 + k0 + q4 * 8);
                short8 b = *(const short8*)(qp_s + l15 * 776 + k0 + q4 * 8);
                aacc = __builtin_amdgcn_mfma_f32_16x16x32_bf16(a, b, aacc, 0, 0, 0);
            }
            if (l15 < 12) {
#pragma unroll
                for (int r = 0; r < 4; ++r) {
                    int tl = q4 * 4 + r;
                    float a = 0.125f * (aacc[r] + qb_s[l15]);
                    if (msk_s[tc * 16 + tl] == 0) a = -1e30f;
                    aff_s[tl * 13 + l15] = a;
                }
            }
        }
        __syncthreads();
        // ---- phase C: online softmax update ----
        if (tid < 12) {
            int h = tid;
            float mold = mh_s[h], mc = mold;
#pragma unroll
            for (int tl = 0; tl < 16; ++tl) mc = fmaxf(mc, aff_s[tl * 13 + h]);
            float al = __expf(mold - mc);
            float ls = 0.f;
#pragma unroll
            for (int tl = 0; tl < 16; ++tl) {
                float p = __expf(aff_s[tl * 13 + h] - mc);
                aff_s[tl * 13 + h] = p;
                ls += p;
            }
            lh_s[h] = lh_s[h] * al + ls;
            mh_s[h] = mc;
            al_s[h] = al;
        }
        __syncthreads();
        // ---- phase D: sacc = sacc*alpha + p^T @ yn via MFMA ----
        short8 af;
#pragma unroll
        for (int jj = 0; jj < 8; ++jj) {
            int tl = q4 * 8 + jj;
            float p = (tl < 16 && l15 < 12) ? aff_s[tl * 13 + l15] : 0.f;
            af[jj] = (short)f2b(p);
        }
        float alph[4];
#pragma unroll
        for (int r = 0; r < 4; ++r) alph[r] = al_s[q4 * 4 + r];
#pragma unroll
        for (int jt = 0; jt < 12; ++jt) {
            int nn0 = (wid * 12 + jt) * 16;
            short8 bf;
#pragma unroll
            for (int jj = 0; jj < 8; ++jj) {
                int tl = q4 * 8 + jj;
                bf[jj] = (tl < 16) ? (short)yn_s[tl * 776 + nn0 + l15] : (short)0;
            }
            f32x4 a4 = sacc[jt];
#pragma unroll
            for (int r = 0; r < 4; ++r) a4[r] *= alph[r];
            sacc[jt] = __builtin_amdgcn_mfma_f32_16x16x32_bf16(af, bf, a4, 0, 0, 0);
        }
        __syncthreads();
    }
    // epilogue: normalize and write s[n, h*768+c]
    if (q4 < 3) {
#pragma unroll
        for (int jt = 0; jt < 12; ++jt) {
            int c = (wid * 12 + jt) * 16 + l15;
#pragma unroll
            for (int r = 0; r < 4; ++r) {
                int hh = q4 * 4 + r;
                s_out[(long)n * (HH * CC) + hh * CC + c] = f2b(sacc[jt][r] / lh_s[hh]);
            }
        }
    }
}

// ---------------- host ----------------

extern "C" void kernel_launch(void* const* d_in, const int* in_sizes, int n_in,
                              void* d_out, int out_size, void* d_ws, size_t ws_size,
                              hipStream_t stream) {
    const float* inf    = (const float*)d_in[0];
    const int* mask     = (const int*)d_in[1];
    const float* cls    = (const float*)d_in[2];
    const float* conv_w = (const float*)d_in[3];
    const float* conv_b = (const float*)d_in[4];
    const float* pos    = (const float*)d_in[5];
    const float* wq     = (const float*)d_in[6];
    const float* bq     = (const float*)d_in[7];
    const float* wk     = (const float*)d_in[8];
    const float* bk     = (const float*)d_in[9];
    const float* wv     = (const float*)d_in[10];
    const float* bv     = (const float*)d_in[11];
    const float* wo     = (const float*)d_in[12];
    const float* bo     = (const float*)d_in[13];
    const float* fc1w   = (const float*)d_in[14];
    const float* fc1b   = (const float*)d_in[15];
    const float* fc2w   = (const float*)d_in[16];
    const float* fc2b   = (const float*)d_in[17];
    const float* ln1g   = (const float*)d_in[18];
    const float* ln1b   = (const float*)d_in[19];
    const float* ln2g   = (const float*)d_in[20];
    const float* ln2b   = (const float*)d_in[21];
    const float* ln3g   = (const float*)d_in[22];
    const float* ln3b   = (const float*)d_in[23];

    char* ws = (char*)d_ws;
    float* x     = (float*)(ws + 0);             // 3,145,728 B
    u16* xn      = (u16*)(ws + 3145728);         // 1,572,864
    u16* qbuf    = (u16*)(ws + 4718592);         // 1,572,864
    float* qb    = (float*)(ws + 6291456);       // 49,152
    u16* qproj   = (u16*)(ws + 6340608);         // 18,874,368
    u16* sbuf    = (u16*)(ws + 25214976);        // 18,874,368
    u16* mix     = (u16*)(ws + 44089344);        // 1,572,864
    u16* g       = (u16*)(ws + 45662208);        // 6,291,456
    u16* wkT     = (u16*)(ws + 51953664);        // 4,718,592  -> total 56,672,256 B

    const int LCC = CC * CC;       // 589824
    const int LCM = CC * MLP;      // 2359296

    init_x_kernel<<<dim3(3072), dim3(256), 0, stream>>>(cls, x);
    transpose_k_kernel<<<dim3(24, 24, 4), dim3(256), 0, stream>>>(wk, wkT);

    for (int l = 0; l < 4; ++l) {
        const float* wq_l = wq + (long)l * LCC;
        const float* wv_l = wv + (long)l * LCC;
        const float* wo_l = wo + (long)l * LCC;
        const u16* wkT_l = wkT + (long)l * LCC;
        const float* fc1w_l = fc1w + (long)l * LCM;
        const float* fc2w_l = fc2w + (long)l * LCM;

        // qn = LN1(x); q = qn@wq + bq
        ln_kernel<<<dim3(1024), dim3(256), 0, stream>>>(x, ln1g + l * CC, ln1b + l * CC, xn);
        gemm_kernel<0, 0, 1, 1><<<dim3(12, 16, 1), dim3(256), 0, stream>>>(
            xn, CC, 0, wq_l, CC, 0, qbuf, CC, 0, bq + l * CC, 0, CC);
        // qb[n,h]
        qb_kernel<<<dim3(3072), dim3(256), 0, stream>>>(qbuf, bk + l * CC, qb);
        // qproj[n,h,c] = q_h @ wk_h^T   (z = head)
        gemm_kernel<0, 0, 0, 0><<<dim3(12, 16, 12), dim3(256), 0, stream>>>(
            qbuf, CC, 64, wkT_l, CC, 64 * CC, qproj, HH * CC, CC, nullptr, 0, 64);
        // fused conv+LN3+attention -> s[n,h,c]
        attn_kernel<<<dim3(1024), dim3(256), 0, stream>>>(
            inf, mask, conv_w + l * CC * 3, conv_b + l * CC, pos + (long)l * TT * CC,
            ln3g + l * CC, ln3b + l * CC, qproj, qb, sbuf);
        // mix[n, h*64+d] = s[n,h,:] @ wv_h + bv_h   (z = head)
        gemm_kernel<0, 0, 1, 1><<<dim3(1, 16, 12), dim3(256), 0, stream>>>(
            sbuf, HH * CC, CC, wv_l, CC, 64, mix, CC, 64, bv + l * CC, 64, CC);
        // x += mix @ wo + bo
        gemm_kernel<1, 0, 1, 1><<<dim3(12, 16, 1), dim3(256), 0, stream>>>(
            mix, CC, 0, wo_l, CC, 0, x, CC, 0, bo + l * CC, 0, CC);
        // MLP
        ln_kernel<<<dim3(1024), dim3(256), 0, stream>>>(x, ln2g + l * CC, ln2b + l * CC, xn);
        gemm_kernel<0, 1, 1, 1><<<dim3(48, 16, 1), dim3(256), 0, stream>>>(
            xn, CC, 0, fc1w_l, MLP, 0, g, MLP, 0, fc1b + l * MLP, 0, CC);
        gemm_kernel<1, 0, 1, 1><<<dim3(12, 16, 1), dim3(256), 0, stream>>>(
            g, MLP, 0, fc2w_l, CC, 0, x, CC, 0, fc2b + l * CC, 0, MLP);
    }

    store_out_kernel<<<dim3(3072), dim3(256), 0, stream>>>(x, (float*)d_out);
}

// Round 2
// 1511.160 us; speedup vs baseline: 1.0598x; 1.0598x over previous
//
#include <hip/hip_runtime.h>

typedef unsigned short u16;
typedef __attribute__((ext_vector_type(8))) short short8;
typedef __attribute__((ext_vector_type(4))) float f32x4;

#define NB 1024
#define TT 64
#define CC 768
#define HH 12
#define HD 64
#define MLP 3072

__device__ __forceinline__ float b2f(u16 u) {
    return __uint_as_float(((unsigned)u) << 16);
}
__device__ __forceinline__ u16 f2b(float f) {
    unsigned u = __float_as_uint(f);
    unsigned r = (u + 0x7fff + ((u >> 16) & 1)) >> 16;
    return (u16)r;
}

__device__ __forceinline__ void block_reduce2(float& a, float& b, float* rbuf, int tid) {
#pragma unroll
    for (int off = 32; off > 0; off >>= 1) {
        a += __shfl_down(a, off, 64);
        b += __shfl_down(b, off, 64);
    }
    int wid = tid >> 6, lane = tid & 63;
    if (lane == 0) { rbuf[wid] = a; rbuf[wid + 4] = b; }
    __syncthreads();
    a = rbuf[0] + rbuf[1] + rbuf[2] + rbuf[3];
    b = rbuf[4] + rbuf[5] + rbuf[6] + rbuf[7];
    __syncthreads();
}

// ---------------- init / misc kernels ----------------

__global__ __launch_bounds__(256) void init_x_kernel(const float* __restrict__ cls, float* __restrict__ x) {
    int idx = blockIdx.x * 256 + threadIdx.x;  // < 786432
    x[idx] = cls[idx % CC];
}

__global__ __launch_bounds__(256) void store_out_kernel(const float* __restrict__ x, float* __restrict__ out) {
    int idx = blockIdx.x * 256 + threadIdx.x;
    out[idx] = x[idx];
}

// wkT[l][i][c] = wk[l][c][i], fp32 -> bf16
__global__ __launch_bounds__(256) void transpose_k_kernel(const float* __restrict__ wk, u16* __restrict__ wkT) {
    __shared__ float tile[32][33];
    int l = blockIdx.z;
    const float* src = wk + (long)l * (CC * CC);
    u16* dst = wkT + (long)l * (CC * CC);
    int i0 = blockIdx.x * 32, c0 = blockIdx.y * 32;
    int tx = threadIdx.x & 31, ty = threadIdx.x >> 5;  // ty 0..7
#pragma unroll
    for (int u = 0; u < 4; ++u)
        tile[ty + 8 * u][tx] = src[(long)(c0 + ty + 8 * u) * CC + i0 + tx];
    __syncthreads();
#pragma unroll
    for (int u = 0; u < 4; ++u)
        dst[(long)(i0 + ty + 8 * u) * CC + c0 + tx] = f2b(tile[tx][ty + 8 * u]);
}

// LN over C=768 of fp32 x -> bf16 out, with fp32 gamma/beta
__global__ __launch_bounds__(256) void ln_kernel(const float* __restrict__ x, const float* __restrict__ g,
                                                 const float* __restrict__ b, u16* __restrict__ out) {
    __shared__ float rbuf[8];
    int n = blockIdx.x, tid = threadIdx.x;
    const float* xr = x + (long)n * CC;
    float v0 = xr[tid], v1 = xr[tid + 256], v2 = xr[tid + 512];
    float s = v0 + v1 + v2, ss = v0 * v0 + v1 * v1 + v2 * v2;
    block_reduce2(s, ss, rbuf, tid);
    float mu = s * (1.0f / 768.0f);
    float rs = rsqrtf(ss * (1.0f / 768.0f) - mu * mu + 1e-5f);
    u16* orow = out + (long)n * CC;
    orow[tid]       = f2b((v0 - mu) * rs * g[tid]       + b[tid]);
    orow[tid + 256] = f2b((v1 - mu) * rs * g[tid + 256] + b[tid + 256]);
    orow[tid + 512] = f2b((v2 - mu) * rs * g[tid + 512] + b[tid + 512]);
}

// qb[n*12+h] = sum_d q[n, h*64+d] * bk[h*64+d]
__global__ __launch_bounds__(256) void qb_kernel(const u16* __restrict__ q, const float* __restrict__ bk,
                                                 float* __restrict__ qb) {
    int lane = threadIdx.x & 63;
    int idx = blockIdx.x * 4 + (threadIdx.x >> 6);  // n*12+h
    int n = idx / 12, h = idx - n * 12;
    float v = b2f(q[(long)n * CC + h * 64 + lane]) * bk[h * 64 + lane];
#pragma unroll
    for (int off = 32; off > 0; off >>= 1) v += __shfl_down(v, off, 64);
    if (lane == 0) qb[idx] = v;
}

// ---------------- generic MFMA GEMM (64x64 tile, K-step 32) ----------------
template <int ACC_F32, int GELU, int HAS_BIAS, int B_F32>
__global__ __launch_bounds__(256) void gemm_kernel(const u16* __restrict__ A, int lda, long a_zoff,
                                                   const void* __restrict__ Bv, int ldb, long b_zoff,
                                                   void* __restrict__ Cout, int ldc, long c_zoff,
                                                   const float* __restrict__ bias, long bias_zoff,
                                                   int K) {
    __shared__ u16 As[64 * 40];
    __shared__ u16 Bs[64 * 40];
    const int tid = threadIdx.x;
    const int z = blockIdx.z;
    A += (long)z * a_zoff;
    const float* Bf = B_F32 ? ((const float*)Bv + (long)z * b_zoff) : nullptr;
    const u16* Bh = B_F32 ? nullptr : ((const u16*)Bv + (long)z * b_zoff);
    const float* bias_p = HAS_BIAS ? bias + (long)z * bias_zoff : nullptr;
    const long c_base = (long)z * c_zoff;
    const int m0 = blockIdx.y * 64;
    const int n0 = blockIdx.x * 64;

    const int am = tid >> 2;
    const int ak = (tid & 3) * 8;
    const int bn = tid & 63;
    const int bk = (tid >> 6) * 8;

    const int lane = tid & 63;
    const int wid = tid >> 6;
    const int wm = (wid >> 1) * 32, wn = (wid & 1) * 32;
    const int l15 = lane & 15, q4 = lane >> 4;

    f32x4 acc[2][2] = {};

    for (int k0 = 0; k0 < K; k0 += 32) {
        int4 av = *(const int4*)(A + (long)(m0 + am) * lda + k0 + ak);
        unsigned bv0, bv1, bv2, bv3;
        if (B_F32) {
            const float* bp = Bf + (long)(k0 + bk) * ldb + n0 + bn;
            u16 e0 = f2b(bp[0]);
            u16 e1 = f2b(bp[(long)ldb]);
            u16 e2 = f2b(bp[(long)ldb * 2]);
            u16 e3 = f2b(bp[(long)ldb * 3]);
            u16 e4 = f2b(bp[(long)ldb * 4]);
            u16 e5 = f2b(bp[(long)ldb * 5]);
            u16 e6 = f2b(bp[(long)ldb * 6]);
            u16 e7 = f2b(bp[(long)ldb * 7]);
            bv0 = (unsigned)e0 | ((unsigned)e1 << 16); bv1 = (unsigned)e2 | ((unsigned)e3 << 16);
            bv2 = (unsigned)e4 | ((unsigned)e5 << 16); bv3 = (unsigned)e6 | ((unsigned)e7 << 16);
        } else {
            const u16* bp = Bh + (long)(k0 + bk) * ldb + n0 + bn;
            unsigned e0 = bp[0];
            unsigned e1 = bp[(long)ldb];
            unsigned e2 = bp[(long)ldb * 2];
            unsigned e3 = bp[(long)ldb * 3];
            unsigned e4 = bp[(long)ldb * 4];
            unsigned e5 = bp[(long)ldb * 5];
            unsigned e6 = bp[(long)ldb * 6];
            unsigned e7 = bp[(long)ldb * 7];
            bv0 = e0 | (e1 << 16); bv1 = e2 | (e3 << 16);
            bv2 = e4 | (e5 << 16); bv3 = e6 | (e7 << 16);
        }
        __syncthreads();
        *(int4*)(As + am * 40 + ak) = av;
        int4 bvv; bvv.x = (int)bv0; bvv.y = (int)bv1; bvv.z = (int)bv2; bvv.w = (int)bv3;
        *(int4*)(Bs + bn * 40 + bk) = bvv;  // Bs[n][k]
        __syncthreads();

        short8 a_f[2], b_f[2];
        a_f[0] = *(const short8*)(As + (wm + l15) * 40 + q4 * 8);
        a_f[1] = *(const short8*)(As + (wm + 16 + l15) * 40 + q4 * 8);
        b_f[0] = *(const short8*)(Bs + (wn + l15) * 40 + q4 * 8);
        b_f[1] = *(const short8*)(Bs + (wn + 16 + l15) * 40 + q4 * 8);
#pragma unroll
        for (int i = 0; i < 2; ++i)
#pragma unroll
            for (int j = 0; j < 2; ++j)
                acc[i][j] = __builtin_amdgcn_mfma_f32_16x16x32_bf16(a_f[i], b_f[j], acc[i][j], 0, 0, 0);
    }

#pragma unroll
    for (int i = 0; i < 2; ++i) {
#pragma unroll
        for (int j = 0; j < 2; ++j) {
            int row = m0 + wm + i * 16 + q4 * 4;
            int col = n0 + wn + j * 16 + l15;
            float bias_v = 0.f;
            if (HAS_BIAS) bias_v = bias_p[col];
#pragma unroll
            for (int r = 0; r < 4; ++r) {
                float v = acc[i][j][r] + bias_v;
                if (GELU) v = v / (1.0f + __expf(-1.702f * v));
                if (ACC_F32) {
                    float* Cf = (float*)Cout + c_base;
                    Cf[(long)(row + r) * ldc + col] += v;
                } else {
                    u16* Cb = (u16*)Cout + c_base;
                    Cb[(long)(row + r) * ldc + col] = f2b(v);
                }
            }
        }
    }
}

// ---------------- fused attention kernel v3 (single-pass, 512 threads, 1 block/n) ----------------
// Phase A: 8 waves x 8 rows: conv+residual+pe+LN3 -> yn_s (all 64 rows in LDS)
// Phase B: aff = yn @ qp^T via MFMA: 4 row-tiles x 2 K-halves across 8 waves -> aff_p partials
// Phase C: full softmax over t (192 threads), p pre-normalized by 1/l -> p_s
// Phase D: s = p^T @ yn via MFMA, 6 column-tiles per wave, K=64 (2 k-steps)
__global__ __launch_bounds__(512, 2) void attn_kernel(const float* __restrict__ inf, const int* __restrict__ mask,
                                                      const float* __restrict__ cw, const float* __restrict__ cb,
                                                      const float* __restrict__ pe, const float* __restrict__ g3,
                                                      const float* __restrict__ b3, const u16* __restrict__ qproj,
                                                      const float* __restrict__ qb, u16* __restrict__ s_out) {
    __shared__ u16 yn_s[64 * 776];     // 99328 B
    __shared__ u16 qp_s[12 * 776];     // 18624 B
    __shared__ float aff_p[2 * 64 * 16];  // 8192 B  [kh][t][h]
    __shared__ float p_s[64 * 16];     // 4096 B   [t][h], pre-normalized
    __shared__ float qb_s[12];
    __shared__ int msk_s[64];

    const int tid = threadIdx.x;
    const int lane = tid & 63;
    const int w = tid >> 6;            // wave 0..7
    const int l15 = lane & 15, q4 = lane >> 4;
    const int n = blockIdx.x;
    const long ibase = (long)n * (TT * CC);
    const int c0 = lane * 4;           // channels c0+256j+q, j=0..2, q=0..3

    // stage qproj[n] (12 rows of 768 bf16) into qp_s (776-stride)
    for (int idx = tid * 8; idx < HH * CC; idx += 512 * 8) {
        uint4 v = *(const uint4*)(qproj + (long)n * (HH * CC) + idx);
        int h = idx / CC, c = idx - h * CC;
        *(uint4*)(qp_s + h * 776 + c) = v;
    }
    if (tid < 12) qb_s[tid] = qb[n * 12 + tid];
    if (tid < 64) msk_s[tid] = mask[n * TT + tid];

    // per-thread conv/LN constants for its 12 channels
    float cw0a[12], cw1a[12], cw2a[12], cba[12], ga[12], ba[12];
#pragma unroll
    for (int j = 0; j < 3; ++j) {
        int c = c0 + 256 * j;
        *(float4*)(cba + 4 * j) = *(const float4*)(cb + c);
        *(float4*)(ga + 4 * j) = *(const float4*)(g3 + c);
        *(float4*)(ba + 4 * j) = *(const float4*)(b3 + c);
#pragma unroll
        for (int q = 0; q < 4; ++q) {
            cw0a[j * 4 + q] = cw[(c + q) * 3 + 0];
            cw1a[j * 4 + q] = cw[(c + q) * 3 + 1];
            cw2a[j * 4 + q] = cw[(c + q) * 3 + 2];
        }
    }

    // ---- phase A: 8 rows per wave (sliding conv window), wave-level reductions only ----
    {
        const int t0 = w * 8;
        float pva[12], cva[12], nva[12];
#pragma unroll
        for (int j = 0; j < 3; ++j) {
            int c = c0 + 256 * j;
            if (t0 > 0)
                *(float4*)(pva + 4 * j) = *(const float4*)(inf + ibase + (long)(t0 - 1) * CC + c);
            else
                *(float4*)(pva + 4 * j) = make_float4(0.f, 0.f, 0.f, 0.f);
            *(float4*)(cva + 4 * j) = *(const float4*)(inf + ibase + (long)t0 * CC + c);
        }
#pragma unroll
        for (int r = 0; r < 8; ++r) {
            const int t = t0 + r;
#pragma unroll
            for (int j = 0; j < 3; ++j) {
                int c = c0 + 256 * j;
                if (t < 63)
                    *(float4*)(nva + 4 * j) = *(const float4*)(inf + ibase + (long)(t + 1) * CC + c);
                else
                    *(float4*)(nva + 4 * j) = make_float4(0.f, 0.f, 0.f, 0.f);
            }
            float pev[12];
#pragma unroll
            for (int j = 0; j < 3; ++j)
                *(float4*)(pev + 4 * j) = *(const float4*)(pe + (long)t * CC + c0 + 256 * j);
            float y[12];
            float sm = 0.f, sq = 0.f;
#pragma unroll
            for (int q = 0; q < 12; ++q) {
                float yy = cva[q] + cw0a[q] * pva[q] + cw1a[q] * cva[q] + cw2a[q] * nva[q] + cba[q] + pev[q];
                y[q] = yy;
                sm += yy;
                sq += yy * yy;
            }
#pragma unroll
            for (int off = 32; off > 0; off >>= 1) {
                sm += __shfl_xor(sm, off, 64);
                sq += __shfl_xor(sq, off, 64);
            }
            float mu = sm * (1.0f / 768.0f);
            float rs = rsqrtf(sq * (1.0f / 768.0f) - mu * mu + 1e-5f);
#pragma unroll
            for (int j = 0; j < 3; ++j) {
                int c = c0 + 256 * j;
                unsigned w0 = (unsigned)f2b((y[j * 4 + 0] - mu) * rs * ga[j * 4 + 0] + ba[j * 4 + 0]) |
                              ((unsigned)f2b((y[j * 4 + 1] - mu) * rs * ga[j * 4 + 1] + ba[j * 4 + 1]) << 16);
                unsigned w1 = (unsigned)f2b((y[j * 4 + 2] - mu) * rs * ga[j * 4 + 2] + ba[j * 4 + 2]) |
                              ((unsigned)f2b((y[j * 4 + 3] - mu) * rs * ga[j * 4 + 3] + ba[j * 4 + 3]) << 16);
                *(uint2*)(yn_s + t * 776 + c) = make_uint2(w0, w1);
            }
#pragma unroll
            for (int q = 0; q < 12; ++q) { pva[q] = cva[q]; cva[q] = nva[q]; }
        }
    }
    __syncthreads();

    // ---- phase B: aff partials via MFMA; wave w: rows (w&3)*16..+16, K-half (w>>2) ----
    {
        const int rows16 = (w & 3) * 16;
        const int kh = w >> 2;
        f32x4 acc0 = {0.f, 0.f, 0.f, 0.f}, acc1 = {0.f, 0.f, 0.f, 0.f};
        const int kbase = kh * 384;
#pragma unroll
        for (int k0 = 0; k0 < 384; k0 += 64) {
            short8 a0 = *(const short8*)(yn_s + (rows16 + l15) * 776 + kbase + k0 + q4 * 8);
            short8 b0 = *(const short8*)(qp_s + l15 * 776 + kbase + k0 + q4 * 8);
            acc0 = __builtin_amdgcn_mfma_f32_16x16x32_bf16(a0, b0, acc0, 0, 0, 0);
            short8 a1 = *(const short8*)(yn_s + (rows16 + l15) * 776 + kbase + k0 + 32 + q4 * 8);
            short8 b1 = *(const short8*)(qp_s + l15 * 776 + kbase + k0 + 32 + q4 * 8);
            acc1 = __builtin_amdgcn_mfma_f32_16x16x32_bf16(a1, b1, acc1, 0, 0, 0);
        }
        // C/D layout: col(h) = l15, row(t-within-tile) = q4*4 + r
#pragma unroll
        for (int r = 0; r < 4; ++r)
            aff_p[kh * 1024 + (rows16 + q4 * 4 + r) * 16 + l15] = acc0[r] + acc1[r];
    }
    __syncthreads();

    // ---- phase C: full softmax over t per head; p pre-normalized ----
    if (tid < 256) {
        const int h = tid >> 4, tg = tid & 15;
        if (h < 12) {  // wave-uniform: each 16-lane group has one h; waves 0-2 take this branch
            float a[4];
#pragma unroll
            for (int i = 0; i < 4; ++i) {
                int t = tg * 4 + i;
                float v = 0.125f * (aff_p[t * 16 + h] + aff_p[1024 + t * 16 + h] + qb_s[h]);
                if (msk_s[t] == 0) v = -1e30f;
                a[i] = v;
            }
            float m = fmaxf(fmaxf(a[0], a[1]), fmaxf(a[2], a[3]));
#pragma unroll
            for (int off = 1; off < 16; off <<= 1) m = fmaxf(m, __shfl_xor(m, off, 64));
            float p[4], s = 0.f;
#pragma unroll
            for (int i = 0; i < 4; ++i) { p[i] = __expf(a[i] - m); s += p[i]; }
#pragma unroll
            for (int off = 1; off < 16; off <<= 1) s += __shfl_xor(s, off, 64);
            float rinv = 1.0f / s;
#pragma unroll
            for (int i = 0; i < 4; ++i) p_s[(tg * 4 + i) * 16 + h] = p[i] * rinv;
        } else {  // zero pad columns 12..15 (wave 3)
#pragma unroll
            for (int i = 0; i < 4; ++i) p_s[(tg * 4 + i) * 16 + h] = 0.f;
        }
    }
    __syncthreads();

    // ---- phase D: s = p^T @ yn via MFMA; wave w covers channels [w*96, w*96+96) ----
    {
        short8 af[2];
#pragma unroll
        for (int ks = 0; ks < 2; ++ks)
#pragma unroll
            for (int jj = 0; jj < 8; ++jj) {
                int t = ks * 32 + q4 * 8 + jj;
                af[ks][jj] = (short)f2b(p_s[t * 16 + l15]);
            }
        f32x4 dacc[6] = {};
        const int c0w = w * 96;
#pragma unroll
        for (int nt = 0; nt < 6; ++nt) {
            const int cb = c0w + nt * 16 + l15;
            short8 bf;
#pragma unroll
            for (int jj = 0; jj < 8; ++jj) bf[jj] = (short)yn_s[(q4 * 8 + jj) * 776 + cb];
            dacc[nt] = __builtin_amdgcn_mfma_f32_16x16x32_bf16(af[0], bf, dacc[nt], 0, 0, 0);
#pragma unroll
            for (int jj = 0; jj < 8; ++jj) bf[jj] = (short)yn_s[(32 + q4 * 8 + jj) * 776 + cb];
            dacc[nt] = __builtin_amdgcn_mfma_f32_16x16x32_bf16(af[1], bf, dacc[nt], 0, 0, 0);
        }
        // epilogue: rows = h = q4*4+r (valid h<12 -> q4<3), col = c0w + nt*16 + l15
        if (q4 < 3) {
#pragma unroll
            for (int nt = 0; nt < 6; ++nt) {
                const int c = c0w + nt * 16 + l15;
#pragma unroll
                for (int r = 0; r < 4; ++r) {
                    int hh = q4 * 4 + r;
                    s_out[(long)n * (HH * CC) + hh * CC + c] = f2b(dacc[nt][r]);
                }
            }
        }
    }
}

// ---------------- host ----------------

extern "C" void kernel_launch(void* const* d_in, const int* in_sizes, int n_in,
                              void* d_out, int out_size, void* d_ws, size_t ws_size,
                              hipStream_t stream) {
    const float* inf    = (const float*)d_in[0];
    const int* mask     = (const int*)d_in[1];
    const float* cls    = (const float*)d_in[2];
    const float* conv_w = (const float*)d_in[3];
    const float* conv_b = (const float*)d_in[4];
    const float* pos    = (const float*)d_in[5];
    const float* wq     = (const float*)d_in[6];
    const float* bq     = (const float*)d_in[7];
    const float* wk     = (const float*)d_in[8];
    const float* bk     = (const float*)d_in[9];
    const float* wv     = (const float*)d_in[10];
    const float* bv     = (const float*)d_in[11];
    const float* wo     = (const float*)d_in[12];
    const float* bo     = (const float*)d_in[13];
    const float* fc1w   = (const float*)d_in[14];
    const float* fc1b   = (const float*)d_in[15];
    const float* fc2w   = (const float*)d_in[16];
    const float* fc2b   = (const float*)d_in[17];
    const float* ln1g   = (const float*)d_in[18];
    const float* ln1b   = (const float*)d_in[19];
    const float* ln2g   = (const float*)d_in[20];
    const float* ln2b   = (const float*)d_in[21];
    const float* ln3g   = (const float*)d_in[22];
    const float* ln3b   = (const float*)d_in[23];

    char* ws = (char*)d_ws;
    float* x     = (float*)(ws + 0);             // 3,145,728 B
    u16* xn      = (u16*)(ws + 3145728);         // 1,572,864
    u16* qbuf    = (u16*)(ws + 4718592);         // 1,572,864
    float* qb    = (float*)(ws + 6291456);       // 49,152
    u16* qproj   = (u16*)(ws + 6340608);         // 18,874,368
    u16* sbuf    = (u16*)(ws + 25214976);        // 18,874,368
    u16* mix     = (u16*)(ws + 44089344);        // 1,572,864
    u16* g       = (u16*)(ws + 45662208);        // 6,291,456
    u16* wkT     = (u16*)(ws + 51953664);        // 4,718,592  -> total 56,672,256 B

    const int LCC = CC * CC;       // 589824
    const int LCM = CC * MLP;      // 2359296

    init_x_kernel<<<dim3(3072), dim3(256), 0, stream>>>(cls, x);
    transpose_k_kernel<<<dim3(24, 24, 4), dim3(256), 0, stream>>>(wk, wkT);

    for (int l = 0; l < 4; ++l) {
        const float* wq_l = wq + (long)l * LCC;
        const float* wv_l = wv + (long)l * LCC;
        const float* wo_l = wo + (long)l * LCC;
        const u16* wkT_l = wkT + (long)l * LCC;
        const float* fc1w_l = fc1w + (long)l * LCM;
        const float* fc2w_l = fc2w + (long)l * LCM;

        // qn = LN1(x); q = qn@wq + bq
        ln_kernel<<<dim3(1024), dim3(256), 0, stream>>>(x, ln1g + l * CC, ln1b + l * CC, xn);
        gemm_kernel<0, 0, 1, 1><<<dim3(12, 16, 1), dim3(256), 0, stream>>>(
            xn, CC, 0, wq_l, CC, 0, qbuf, CC, 0, bq + l * CC, 0, CC);
        // qb[n,h]
        qb_kernel<<<dim3(3072), dim3(256), 0, stream>>>(qbuf, bk + l * CC, qb);
        // qproj[n,h,c] = q_h @ wk_h^T   (z = head)
        gemm_kernel<0, 0, 0, 0><<<dim3(12, 16, 12), dim3(256), 0, stream>>>(
            qbuf, CC, 64, wkT_l, CC, 64 * CC, qproj, HH * CC, CC, nullptr, 0, 64);
        // fused conv+LN3+attention -> s[n,h,c]
        attn_kernel<<<dim3(1024), dim3(512), 0, stream>>>(
            inf, mask, conv_w + l * CC * 3, conv_b + l * CC, pos + (long)l * TT * CC,
            ln3g + l * CC, ln3b + l * CC, qproj, qb, sbuf);
        // mix[n, h*64+d] = s[n,h,:] @ wv_h + bv_h   (z = head)
        gemm_kernel<0, 0, 1, 1><<<dim3(1, 16, 12), dim3(256), 0, stream>>>(
            sbuf, HH * CC, CC, wv_l, CC, 64, mix, CC, 64, bv + l * CC, 64, CC);
        // x += mix @ wo + bo
        gemm_kernel<1, 0, 1, 1><<<dim3(12, 16, 1), dim3(256), 0, stream>>>(
            mix, CC, 0, wo_l, CC, 0, x, CC, 0, bo + l * CC, 0, CC);
        // MLP
        ln_kernel<<<dim3(1024), dim3(256), 0, stream>>>(x, ln2g + l * CC, ln2b + l * CC, xn);
        gemm_kernel<0, 1, 1, 1><<<dim3(48, 16, 1), dim3(256), 0, stream>>>(
            xn, CC, 0, fc1w_l, MLP, 0, g, MLP, 0, fc1b + l * MLP, 0, CC);
        gemm_kernel<1, 0, 1, 1><<<dim3(12, 16, 1), dim3(256), 0, stream>>>(
            g, MLP, 0, fc2w_l, CC, 0, x, CC, 0, fc2b + l * CC, 0, MLP);
    }

    store_out_kernel<<<dim3(3072), dim3(256), 0, stream>>>(x, (float*)d_out);
}

// Round 3
// 1313.078 us; speedup vs baseline: 1.2197x; 1.1509x over previous
//
#include <hip/hip_runtime.h>

typedef unsigned short u16;
typedef __attribute__((ext_vector_type(8))) short short8;
typedef __attribute__((ext_vector_type(4))) float f32x4;

#define NB 1024
#define TT 64
#define CC 768
#define HH 12
#define HD 64
#define MLP 3072

__device__ __forceinline__ float b2f(u16 u) {
    return __uint_as_float(((unsigned)u) << 16);
}
__device__ __forceinline__ u16 f2b(float f) {
    unsigned u = __float_as_uint(f);
    unsigned r = (u + 0x7fff + ((u >> 16) & 1)) >> 16;
    return (u16)r;
}

__device__ __forceinline__ void block_reduce2(float& a, float& b, float* rbuf, int tid) {
#pragma unroll
    for (int off = 32; off > 0; off >>= 1) {
        a += __shfl_down(a, off, 64);
        b += __shfl_down(b, off, 64);
    }
    int wid = tid >> 6, lane = tid & 63;
    if (lane == 0) { rbuf[wid] = a; rbuf[wid + 4] = b; }
    __syncthreads();
    a = rbuf[0] + rbuf[1] + rbuf[2] + rbuf[3];
    b = rbuf[4] + rbuf[5] + rbuf[6] + rbuf[7];
    __syncthreads();
}

// ---------------- init / misc kernels ----------------

__global__ __launch_bounds__(256) void init_x_kernel(const float* __restrict__ cls, float* __restrict__ x) {
    int idx = blockIdx.x * 256 + threadIdx.x;  // < 786432
    x[idx] = cls[idx % CC];
}

__global__ __launch_bounds__(256) void store_out_kernel(const float* __restrict__ x, float* __restrict__ out) {
    int idx = blockIdx.x * 256 + threadIdx.x;
    out[idx] = x[idx];
}

// dst[c][r] (bf16) = src[r][c] (fp32); src is R x C row-major. grid: (C/32, R/32, batch)
__global__ __launch_bounds__(256) void tconv_kernel(const float* __restrict__ src, u16* __restrict__ dst,
                                                    int R, int C) {
    __shared__ float tile[32][33];
    long zoff = (long)blockIdx.z * R * C;
    src += zoff;
    dst += zoff;
    int c0 = blockIdx.x * 32, r0 = blockIdx.y * 32;
    int tx = threadIdx.x & 31, ty = threadIdx.x >> 5;  // ty 0..7
#pragma unroll
    for (int u = 0; u < 4; ++u)
        tile[ty + 8 * u][tx] = src[(long)(r0 + ty + 8 * u) * C + c0 + tx];
    __syncthreads();
#pragma unroll
    for (int u = 0; u < 4; ++u)
        dst[(long)(c0 + ty + 8 * u) * R + r0 + tx] = f2b(tile[tx][ty + 8 * u]);
}

// plain fp32 -> bf16 copy, 4 elements/thread
__global__ __launch_bounds__(256) void cvt_kernel(const float* __restrict__ src, u16* __restrict__ dst) {
    int idx = (blockIdx.x * 256 + threadIdx.x) * 4;
    float4 v = *(const float4*)(src + idx);
    unsigned lo = (unsigned)f2b(v.x) | ((unsigned)f2b(v.y) << 16);
    unsigned hi = (unsigned)f2b(v.z) | ((unsigned)f2b(v.w) << 16);
    *(uint2*)(dst + idx) = make_uint2(lo, hi);
}

// LN over C=768 of fp32 x -> bf16 out, with fp32 gamma/beta
__global__ __launch_bounds__(256) void ln_kernel(const float* __restrict__ x, const float* __restrict__ g,
                                                 const float* __restrict__ b, u16* __restrict__ out) {
    __shared__ float rbuf[8];
    int n = blockIdx.x, tid = threadIdx.x;
    const float* xr = x + (long)n * CC;
    float v0 = xr[tid], v1 = xr[tid + 256], v2 = xr[tid + 512];
    float s = v0 + v1 + v2, ss = v0 * v0 + v1 * v1 + v2 * v2;
    block_reduce2(s, ss, rbuf, tid);
    float mu = s * (1.0f / 768.0f);
    float rs = rsqrtf(ss * (1.0f / 768.0f) - mu * mu + 1e-5f);
    u16* orow = out + (long)n * CC;
    orow[tid]       = f2b((v0 - mu) * rs * g[tid]       + b[tid]);
    orow[tid + 256] = f2b((v1 - mu) * rs * g[tid + 256] + b[tid + 256]);
    orow[tid + 512] = f2b((v2 - mu) * rs * g[tid + 512] + b[tid + 512]);
}

// qb[n*12+h] = sum_d q[n, h*64+d] * bk[h*64+d]
__global__ __launch_bounds__(256) void qb_kernel(const u16* __restrict__ q, const float* __restrict__ bk,
                                                 float* __restrict__ qb) {
    int lane = threadIdx.x & 63;
    int idx = blockIdx.x * 4 + (threadIdx.x >> 6);  // n*12+h
    int n = idx / 12, h = idx - n * 12;
    float v = b2f(q[(long)n * CC + h * 64 + lane]) * bk[h * 64 + lane];
#pragma unroll
    for (int off = 32; off > 0; off >>= 1) v += __shfl_down(v, off, 64);
    if (lane == 0) qb[idx] = v;
}

// ---------------- generic MFMA GEMM (64x64 tile, K-step 32) ----------------
// B is pre-converted bf16 in B^T layout: Bt[n][k], ldb = K-stride of a row.
template <int ACC_F32, int GELU, int HAS_BIAS>
__global__ __launch_bounds__(256) void gemm_kernel(const u16* __restrict__ A, int lda, long a_zoff,
                                                   const u16* __restrict__ Bt, int ldb, long b_zoff,
                                                   void* __restrict__ Cout, int ldc, long c_zoff,
                                                   const float* __restrict__ bias, long bias_zoff,
                                                   int K) {
    __shared__ u16 As[64 * 40];
    __shared__ u16 Bs[64 * 40];
    const int tid = threadIdx.x;
    const int z = blockIdx.z;
    A += (long)z * a_zoff;
    Bt += (long)z * b_zoff;
    const float* bias_p = HAS_BIAS ? bias + (long)z * bias_zoff : nullptr;
    const long c_base = (long)z * c_zoff;
    const int m0 = blockIdx.y * 64;
    const int n0 = blockIdx.x * 64;

    const int am = tid >> 2;          // 0..63: row index for both A and B staging
    const int ak = (tid & 3) * 8;     // k offset within 32-step

    const int lane = tid & 63;
    const int wid = tid >> 6;
    const int wm = (wid >> 1) * 32, wn = (wid & 1) * 32;
    const int l15 = lane & 15, q4 = lane >> 4;

    f32x4 acc[2][2] = {};

    for (int k0 = 0; k0 < K; k0 += 32) {
        int4 av = *(const int4*)(A + (long)(m0 + am) * lda + k0 + ak);
        int4 bv = *(const int4*)(Bt + (long)(n0 + am) * ldb + k0 + ak);
        __syncthreads();
        *(int4*)(As + am * 40 + ak) = av;
        *(int4*)(Bs + am * 40 + ak) = bv;  // Bs[n][k]
        __syncthreads();

        short8 a_f[2], b_f[2];
        a_f[0] = *(const short8*)(As + (wm + l15) * 40 + q4 * 8);
        a_f[1] = *(const short8*)(As + (wm + 16 + l15) * 40 + q4 * 8);
        b_f[0] = *(const short8*)(Bs + (wn + l15) * 40 + q4 * 8);
        b_f[1] = *(const short8*)(Bs + (wn + 16 + l15) * 40 + q4 * 8);
#pragma unroll
        for (int i = 0; i < 2; ++i)
#pragma unroll
            for (int j = 0; j < 2; ++j)
                acc[i][j] = __builtin_amdgcn_mfma_f32_16x16x32_bf16(a_f[i], b_f[j], acc[i][j], 0, 0, 0);
    }

#pragma unroll
    for (int i = 0; i < 2; ++i) {
#pragma unroll
        for (int j = 0; j < 2; ++j) {
            int row = m0 + wm + i * 16 + q4 * 4;
            int col = n0 + wn + j * 16 + l15;
            float bias_v = 0.f;
            if (HAS_BIAS) bias_v = bias_p[col];
#pragma unroll
            for (int r = 0; r < 4; ++r) {
                float v = acc[i][j][r] + bias_v;
                if (GELU) v = v / (1.0f + __expf(-1.702f * v));
                if (ACC_F32) {
                    float* Cf = (float*)Cout + c_base;
                    Cf[(long)(row + r) * ldc + col] += v;
                } else {
                    u16* Cb = (u16*)Cout + c_base;
                    Cb[(long)(row + r) * ldc + col] = f2b(v);
                }
            }
        }
    }
}

// ---------------- fused attention kernel v3 (single-pass, 512 threads, 1 block/n) ----------------
// Phase A: 8 waves x 8 rows: conv+residual+pe+LN3 -> yn_s (all 64 rows in LDS)
// Phase B: aff = yn @ qp^T via MFMA: 4 row-tiles x 2 K-halves across 8 waves -> aff_p partials
// Phase C: full softmax over t (192 threads), p pre-normalized by 1/l -> p_s
// Phase D: s = p^T @ yn via MFMA, 6 column-tiles per wave, K=64 (2 k-steps)
__global__ __launch_bounds__(512, 2) void attn_kernel(const float* __restrict__ inf, const int* __restrict__ mask,
                                                      const float* __restrict__ cw, const float* __restrict__ cb,
                                                      const float* __restrict__ pe, const float* __restrict__ g3,
                                                      const float* __restrict__ b3, const u16* __restrict__ qproj,
                                                      const float* __restrict__ qb, u16* __restrict__ s_out) {
    __shared__ u16 yn_s[64 * 776];     // 99328 B
    __shared__ u16 qp_s[12 * 776];     // 18624 B
    __shared__ float aff_p[2 * 64 * 16];  // 8192 B  [kh][t][h]
    __shared__ float p_s[64 * 16];     // 4096 B   [t][h], pre-normalized
    __shared__ float qb_s[12];
    __shared__ int msk_s[64];

    const int tid = threadIdx.x;
    const int lane = tid & 63;
    const int w = tid >> 6;            // wave 0..7
    const int l15 = lane & 15, q4 = lane >> 4;
    const int n = blockIdx.x;
    const long ibase = (long)n * (TT * CC);
    const int c0 = lane * 4;           // channels c0+256j+q, j=0..2, q=0..3

    // stage qproj[n] (12 rows of 768 bf16) into qp_s (776-stride)
    for (int idx = tid * 8; idx < HH * CC; idx += 512 * 8) {
        uint4 v = *(const uint4*)(qproj + (long)n * (HH * CC) + idx);
        int h = idx / CC, c = idx - h * CC;
        *(uint4*)(qp_s + h * 776 + c) = v;
    }
    if (tid < 12) qb_s[tid] = qb[n * 12 + tid];
    if (tid < 64) msk_s[tid] = mask[n * TT + tid];

    // per-thread conv/LN constants for its 12 channels
    float cw0a[12], cw1a[12], cw2a[12], cba[12], ga[12], ba[12];
#pragma unroll
    for (int j = 0; j < 3; ++j) {
        int c = c0 + 256 * j;
        *(float4*)(cba + 4 * j) = *(const float4*)(cb + c);
        *(float4*)(ga + 4 * j) = *(const float4*)(g3 + c);
        *(float4*)(ba + 4 * j) = *(const float4*)(b3 + c);
#pragma unroll
        for (int q = 0; q < 4; ++q) {
            cw0a[j * 4 + q] = cw[(c + q) * 3 + 0];
            cw1a[j * 4 + q] = cw[(c + q) * 3 + 1];
            cw2a[j * 4 + q] = cw[(c + q) * 3 + 2];
        }
    }

    // ---- phase A: 8 rows per wave (sliding conv window), wave-level reductions only ----
    {
        const int t0 = w * 8;
        float pva[12], cva[12], nva[12];
#pragma unroll
        for (int j = 0; j < 3; ++j) {
            int c = c0 + 256 * j;
            if (t0 > 0)
                *(float4*)(pva + 4 * j) = *(const float4*)(inf + ibase + (long)(t0 - 1) * CC + c);
            else
                *(float4*)(pva + 4 * j) = make_float4(0.f, 0.f, 0.f, 0.f);
            *(float4*)(cva + 4 * j) = *(const float4*)(inf + ibase + (long)t0 * CC + c);
        }
#pragma unroll
        for (int r = 0; r < 8; ++r) {
            const int t = t0 + r;
#pragma unroll
            for (int j = 0; j < 3; ++j) {
                int c = c0 + 256 * j;
                if (t < 63)
                    *(float4*)(nva + 4 * j) = *(const float4*)(inf + ibase + (long)(t + 1) * CC + c);
                else
                    *(float4*)(nva + 4 * j) = make_float4(0.f, 0.f, 0.f, 0.f);
            }
            float pev[12];
#pragma unroll
            for (int j = 0; j < 3; ++j)
                *(float4*)(pev + 4 * j) = *(const float4*)(pe + (long)t * CC + c0 + 256 * j);
            float y[12];
            float sm = 0.f, sq = 0.f;
#pragma unroll
            for (int q = 0; q < 12; ++q) {
                float yy = cva[q] + cw0a[q] * pva[q] + cw1a[q] * cva[q] + cw2a[q] * nva[q] + cba[q] + pev[q];
                y[q] = yy;
                sm += yy;
                sq += yy * yy;
            }
#pragma unroll
            for (int off = 32; off > 0; off >>= 1) {
                sm += __shfl_xor(sm, off, 64);
                sq += __shfl_xor(sq, off, 64);
            }
            float mu = sm * (1.0f / 768.0f);
            float rs = rsqrtf(sq * (1.0f / 768.0f) - mu * mu + 1e-5f);
#pragma unroll
            for (int j = 0; j < 3; ++j) {
                int c = c0 + 256 * j;
                unsigned w0 = (unsigned)f2b((y[j * 4 + 0] - mu) * rs * ga[j * 4 + 0] + ba[j * 4 + 0]) |
                              ((unsigned)f2b((y[j * 4 + 1] - mu) * rs * ga[j * 4 + 1] + ba[j * 4 + 1]) << 16);
                unsigned w1 = (unsigned)f2b((y[j * 4 + 2] - mu) * rs * ga[j * 4 + 2] + ba[j * 4 + 2]) |
                              ((unsigned)f2b((y[j * 4 + 3] - mu) * rs * ga[j * 4 + 3] + ba[j * 4 + 3]) << 16);
                *(uint2*)(yn_s + t * 776 + c) = make_uint2(w0, w1);
            }
#pragma unroll
            for (int q = 0; q < 12; ++q) { pva[q] = cva[q]; cva[q] = nva[q]; }
        }
    }
    __syncthreads();

    // ---- phase B: aff partials via MFMA; wave w: rows (w&3)*16..+16, K-half (w>>2) ----
    {
        const int rows16 = (w & 3) * 16;
        const int kh = w >> 2;
        f32x4 acc0 = {0.f, 0.f, 0.f, 0.f}, acc1 = {0.f, 0.f, 0.f, 0.f};
        const int kbase = kh * 384;
#pragma unroll
        for (int k0 = 0; k0 < 384; k0 += 64) {
            short8 a0 = *(const short8*)(yn_s + (rows16 + l15) * 776 + kbase + k0 + q4 * 8);
            short8 b0 = *(const short8*)(qp_s + l15 * 776 + kbase + k0 + q4 * 8);
            acc0 = __builtin_amdgcn_mfma_f32_16x16x32_bf16(a0, b0, acc0, 0, 0, 0);
            short8 a1 = *(const short8*)(yn_s + (rows16 + l15) * 776 + kbase + k0 + 32 + q4 * 8);
            short8 b1 = *(const short8*)(qp_s + l15 * 776 + kbase + k0 + 32 + q4 * 8);
            acc1 = __builtin_amdgcn_mfma_f32_16x16x32_bf16(a1, b1, acc1, 0, 0, 0);
        }
        // C/D layout: col(h) = l15, row(t-within-tile) = q4*4 + r
#pragma unroll
        for (int r = 0; r < 4; ++r)
            aff_p[kh * 1024 + (rows16 + q4 * 4 + r) * 16 + l15] = acc0[r] + acc1[r];
    }
    __syncthreads();

    // ---- phase C: full softmax over t per head; p pre-normalized ----
    if (tid < 256) {
        const int h = tid >> 4, tg = tid & 15;
        if (h < 12) {  // wave-uniform: each 16-lane group has one h; waves 0-2 take this branch
            float a[4];
#pragma unroll
            for (int i = 0; i < 4; ++i) {
                int t = tg * 4 + i;
                float v = 0.125f * (aff_p[t * 16 + h] + aff_p[1024 + t * 16 + h] + qb_s[h]);
                if (msk_s[t] == 0) v = -1e30f;
                a[i] = v;
            }
            float m = fmaxf(fmaxf(a[0], a[1]), fmaxf(a[2], a[3]));
#pragma unroll
            for (int off = 1; off < 16; off <<= 1) m = fmaxf(m, __shfl_xor(m, off, 64));
            float p[4], s = 0.f;
#pragma unroll
            for (int i = 0; i < 4; ++i) { p[i] = __expf(a[i] - m); s += p[i]; }
#pragma unroll
            for (int off = 1; off < 16; off <<= 1) s += __shfl_xor(s, off, 64);
            float rinv = 1.0f / s;
#pragma unroll
            for (int i = 0; i < 4; ++i) p_s[(tg * 4 + i) * 16 + h] = p[i] * rinv;
        } else {  // zero pad columns 12..15 (wave 3)
#pragma unroll
            for (int i = 0; i < 4; ++i) p_s[(tg * 4 + i) * 16 + h] = 0.f;
        }
    }
    __syncthreads();

    // ---- phase D: s = p^T @ yn via MFMA; wave w covers channels [w*96, w*96+96) ----
    {
        short8 af[2];
#pragma unroll
        for (int ks = 0; ks < 2; ++ks)
#pragma unroll
            for (int jj = 0; jj < 8; ++jj) {
                int t = ks * 32 + q4 * 8 + jj;
                af[ks][jj] = (short)f2b(p_s[t * 16 + l15]);
            }
        f32x4 dacc[6] = {};
        const int c0w = w * 96;
#pragma unroll
        for (int nt = 0; nt < 6; ++nt) {
            const int cb = c0w + nt * 16 + l15;
            short8 bf;
#pragma unroll
            for (int jj = 0; jj < 8; ++jj) bf[jj] = (short)yn_s[(q4 * 8 + jj) * 776 + cb];
            dacc[nt] = __builtin_amdgcn_mfma_f32_16x16x32_bf16(af[0], bf, dacc[nt], 0, 0, 0);
#pragma unroll
            for (int jj = 0; jj < 8; ++jj) bf[jj] = (short)yn_s[(32 + q4 * 8 + jj) * 776 + cb];
            dacc[nt] = __builtin_amdgcn_mfma_f32_16x16x32_bf16(af[1], bf, dacc[nt], 0, 0, 0);
        }
        // epilogue: rows = h = q4*4+r (valid h<12 -> q4<3), col = c0w + nt*16 + l15
        if (q4 < 3) {
#pragma unroll
            for (int nt = 0; nt < 6; ++nt) {
                const int c = c0w + nt * 16 + l15;
#pragma unroll
                for (int r = 0; r < 4; ++r) {
                    int hh = q4 * 4 + r;
                    s_out[(long)n * (HH * CC) + hh * CC + c] = f2b(dacc[nt][r]);
                }
            }
        }
    }
}

// ---------------- host ----------------

extern "C" void kernel_launch(void* const* d_in, const int* in_sizes, int n_in,
                              void* d_out, int out_size, void* d_ws, size_t ws_size,
                              hipStream_t stream) {
    const float* inf    = (const float*)d_in[0];
    const int* mask     = (const int*)d_in[1];
    const float* cls    = (const float*)d_in[2];
    const float* conv_w = (const float*)d_in[3];
    const float* conv_b = (const float*)d_in[4];
    const float* pos    = (const float*)d_in[5];
    const float* wq     = (const float*)d_in[6];
    const float* bq     = (const float*)d_in[7];
    const float* wk     = (const float*)d_in[8];
    const float* bk     = (const float*)d_in[9];
    const float* wv     = (const float*)d_in[10];
    const float* bv     = (const float*)d_in[11];
    const float* wo     = (const float*)d_in[12];
    const float* bo     = (const float*)d_in[13];
    const float* fc1w   = (const float*)d_in[14];
    const float* fc1b   = (const float*)d_in[15];
    const float* fc2w   = (const float*)d_in[16];
    const float* fc2b   = (const float*)d_in[17];
    const float* ln1g   = (const float*)d_in[18];
    const float* ln1b   = (const float*)d_in[19];
    const float* ln2g   = (const float*)d_in[20];
    const float* ln2b   = (const float*)d_in[21];
    const float* ln3g   = (const float*)d_in[22];
    const float* ln3b   = (const float*)d_in[23];

    char* ws = (char*)d_ws;
    float* x     = (float*)(ws + 0);             // 3,145,728 B
    u16* xn      = (u16*)(ws + 3145728);         // 1,572,864
    u16* qbuf    = (u16*)(ws + 4718592);         // 1,572,864
    float* qb    = (float*)(ws + 6291456);       // 49,152
    u16* qproj   = (u16*)(ws + 6340608);         // 18,874,368
    u16* sbuf    = (u16*)(ws + 25214976);        // 18,874,368
    u16* mix     = (u16*)(ws + 44089344);        // 1,572,864
    u16* g       = (u16*)(ws + 45662208);        // 6,291,456
    u16* wbase   = (u16*)(ws + 51953664);        // bf16 weights region

    const long LCC = (long)CC * CC;   // 589824
    const long LCM = (long)CC * MLP;  // 2359296

    // bf16 weight layout (u16 element offsets within wbase):
    //   upfront (all 4 layers): wqT 0 | wkB 4*LCC | wvT 8*LCC | woT 12*LCC | fc1T 16*LCC | fc2T 16*LCC+4*LCM
    //     -> total bytes 51953664 + 2*(16*LCC + 8*LCM) = 108,576,768
    //   per-layer (one layer at a time, reused): wqT 0 | wkB LCC | wvT 2*LCC | woT 3*LCC | fc1T 4*LCC | fc2T 4*LCC+LCM
    //     -> total bytes 51953664 + 2*(4*LCC + 2*LCM) = 66,109,440
    const bool upfront = ws_size >= 108576768ULL;
    u16* wqT  = wbase;
    u16* wkB  = wbase + (upfront ? 4 * LCC : LCC);
    u16* wvT  = wbase + (upfront ? 8 * LCC : 2 * LCC);
    u16* woT  = wbase + (upfront ? 12 * LCC : 3 * LCC);
    u16* fc1T = wbase + (upfront ? 16 * LCC : 4 * LCC);
    u16* fc2T = fc1T + (upfront ? 4 * LCM : LCM);

    init_x_kernel<<<dim3(3072), dim3(256), 0, stream>>>(cls, x);

    if (upfront) {
        tconv_kernel<<<dim3(24, 24, 4), dim3(256), 0, stream>>>(wq, wqT, 768, 768);
        cvt_kernel<<<dim3(2304), dim3(256), 0, stream>>>(wk, wkB);
        tconv_kernel<<<dim3(24, 24, 4), dim3(256), 0, stream>>>(wv, wvT, 768, 768);
        tconv_kernel<<<dim3(24, 24, 4), dim3(256), 0, stream>>>(wo, woT, 768, 768);
        tconv_kernel<<<dim3(96, 24, 4), dim3(256), 0, stream>>>(fc1w, fc1T, 768, 3072);
        tconv_kernel<<<dim3(24, 96, 4), dim3(256), 0, stream>>>(fc2w, fc2T, 3072, 768);
    }

    for (int l = 0; l < 4; ++l) {
        if (!upfront) {
            tconv_kernel<<<dim3(24, 24, 1), dim3(256), 0, stream>>>(wq + l * LCC, wqT, 768, 768);
            cvt_kernel<<<dim3(576), dim3(256), 0, stream>>>(wk + l * LCC, wkB);
            tconv_kernel<<<dim3(24, 24, 1), dim3(256), 0, stream>>>(wv + l * LCC, wvT, 768, 768);
            tconv_kernel<<<dim3(24, 24, 1), dim3(256), 0, stream>>>(wo + l * LCC, woT, 768, 768);
            tconv_kernel<<<dim3(96, 24, 1), dim3(256), 0, stream>>>(fc1w + l * LCM, fc1T, 768, 3072);
            tconv_kernel<<<dim3(24, 96, 1), dim3(256), 0, stream>>>(fc2w + l * LCM, fc2T, 3072, 768);
        }
        const u16* wqT_l  = wqT  + (upfront ? (long)l * LCC : 0);
        const u16* wkB_l  = wkB  + (upfront ? (long)l * LCC : 0);
        const u16* wvT_l  = wvT  + (upfront ? (long)l * LCC : 0);
        const u16* woT_l  = woT  + (upfront ? (long)l * LCC : 0);
        const u16* fc1T_l = fc1T + (upfront ? (long)l * LCM : 0);
        const u16* fc2T_l = fc2T + (upfront ? (long)l * LCM : 0);

        // qn = LN1(x); q = qn@wq + bq
        ln_kernel<<<dim3(1024), dim3(256), 0, stream>>>(x, ln1g + l * CC, ln1b + l * CC, xn);
        gemm_kernel<0, 0, 1><<<dim3(12, 16, 1), dim3(256), 0, stream>>>(
            xn, CC, 0, wqT_l, CC, 0, qbuf, CC, 0, bq + l * CC, 0, CC);
        // qb[n,h]
        qb_kernel<<<dim3(3072), dim3(256), 0, stream>>>(qbuf, bk + l * CC, qb);
        // qproj[n,h,c] = sum_d q[n,h,d] * wk[c, h*64+d]   (z = head; B^T row c is wk row, k-contig)
        gemm_kernel<0, 0, 0><<<dim3(12, 16, 12), dim3(256), 0, stream>>>(
            qbuf, CC, 64, wkB_l, CC, 64, qproj, HH * CC, CC, nullptr, 0, 64);
        // fused conv+LN3+attention -> s[n,h,c]
        attn_kernel<<<dim3(1024), dim3(512), 0, stream>>>(
            inf, mask, conv_w + l * CC * 3, conv_b + l * CC, pos + (long)l * TT * CC,
            ln3g + l * CC, ln3b + l * CC, qproj, qb, sbuf);
        // mix[n, h*64+d] = s[n,h,:] @ wv_h + bv_h   (z = head)
        gemm_kernel<0, 0, 1><<<dim3(1, 16, 12), dim3(256), 0, stream>>>(
            sbuf, HH * CC, CC, wvT_l, CC, 64 * CC, mix, CC, 64, bv + l * CC, 64, CC);
        // x += mix @ wo + bo
        gemm_kernel<1, 0, 1><<<dim3(12, 16, 1), dim3(256), 0, stream>>>(
            mix, CC, 0, woT_l, CC, 0, x, CC, 0, bo + l * CC, 0, CC);
        // MLP
        ln_kernel<<<dim3(1024), dim3(256), 0, stream>>>(x, ln2g + l * CC, ln2b + l * CC, xn);
        gemm_kernel<0, 1, 1><<<dim3(48, 16, 1), dim3(256), 0, stream>>>(
            xn, CC, 0, fc1T_l, CC, 0, g, MLP, 0, fc1b + l * MLP, 0, CC);
        gemm_kernel<1, 0, 1><<<dim3(12, 16, 1), dim3(256), 0, stream>>>(
            g, MLP, 0, fc2T_l, MLP, 0, x, CC, 0, fc2b + l * CC, 0, MLP);
    }

    store_out_kernel<<<dim3(3072), dim3(256), 0, stream>>>(x, (float*)d_out);
}